// Round 1
// baseline (178.255 us; speedup 1.0000x reference)
//
#include <hip/hip_runtime.h>
#include <cmath>

#define NBLK 3456   // 2 * 12 * 12 * 12 blocks of 16^3

// ---- DPP helpers: neighbor value along y (lane row of 16) -------------------
template<int CTRL>
__device__ __forceinline__ int updpp(int oldv, int v) {
  return __builtin_amdgcn_update_dpp(oldv, v, CTRL, 0xF, 0xF, false);
}
// y-1 neighbor (row_shr:1); pad at y==0
__device__ __forceinline__ float nbr_lo_f(float v, float pad, bool ylo) {
  float t = __int_as_float(updpp<0x111>(__float_as_int(pad), __float_as_int(v)));
  return ylo ? pad : t;
}
// y+1 neighbor (row_shl:1); pad at y==15
__device__ __forceinline__ float nbr_hi_f(float v, float pad, bool yhi) {
  float t = __int_as_float(updpp<0x101>(__float_as_int(pad), __float_as_int(v)));
  return yhi ? pad : t;
}
__device__ __forceinline__ unsigned nbr_lo_u(unsigned v, unsigned pad, bool ylo) {
  unsigned t = (unsigned)updpp<0x111>((int)pad, (int)v);
  return ylo ? pad : t;
}
__device__ __forceinline__ unsigned nbr_hi_u(unsigned v, unsigned pad, bool yhi) {
  unsigned t = (unsigned)updpp<0x101>((int)pad, (int)v);
  return yhi ? pad : t;
}

// LDS column layout: float4 chunk c (z=4c..4c+3) of column (x,y) at
// index (c*18 + x+1)*16 + y.  x pad slots at x=-1 -> 0 and x=16 -> 17.
#define COL_IDX(c, xx) (((c)*18 + (xx) + 1)*16 + y)

__global__ __launch_bounds__(256)
void fused_blocks(const float* __restrict__ pred, const float* __restrict__ gtp,
                  float* __restrict__ ws)
{
  __shared__ float4   bufE[1152];   // erode-chain exchange (+INF pads)
  __shared__ float4   bufT[1152];   // laplacian-sum (0 pads) then dilate (-INF pads)
  __shared__ unsigned m_ex[288];    // gt bitmask exchange
  __shared__ float    red[36];

  const int tid = threadIdx.x;
  const int x = tid >> 4;
  const int y = tid & 15;
  const bool ylo = (y == 0), yhi = (y == 15);

  const int b  = blockIdx.x;
  const int n  = b / 1728;
  const int r  = b - n * 1728;
  const int bz = r / 144;
  const int r2 = r - bz * 144;
  const int bx = r2 / 12;
  const int by = r2 - bx * 12;

  const size_t base = (size_t)(n * 192 + bz * 16) * 36864
                    + (size_t)(bx * 16 + x) * 192 + (size_t)(by * 16 + y);

  const float INF = __builtin_inff();

  // pad columns: bufE = +INF (erode identity), bufT = 0 (laplacian sum identity)
  if (tid < 128) {
    const int c  = tid >> 5;
    const int xi = ((tid >> 4) & 1) ? 17 : 0;
    const int yy = tid & 15;
    const int idx = (c * 18 + xi) * 16 + yy;
    bufE[idx] = make_float4(INF, INF, INF, INF);
    bufT[idx] = make_float4(0.f, 0.f, 0.f, 0.f);
  }

  // ---- load pred column ----
  float p[16];
  #pragma unroll
  for (int z = 0; z < 16; ++z) p[z] = pred[base + (size_t)z * 36864];

  float sp2 = 0.f;
  #pragma unroll
  for (int z = 0; z < 16; ++z) sp2 = fmaf(p[z], p[z], sp2);

  #pragma unroll
  for (int c = 0; c < 4; ++c)
    bufE[COL_IDX(c, x)] = make_float4(p[4*c], p[4*c+1], p[4*c+2], p[4*c+3]);

  __syncthreads();                                             // S0

  // ---------------- pred boundary (3^3 laplacian, zero pad) ----------------
  float szy[16];
  {
    float sy[16];
    #pragma unroll
    for (int z = 0; z < 16; ++z) {
      float v = p[z];
      sy[z] = v + nbr_lo_f(v, 0.f, ylo) + nbr_hi_f(v, 0.f, yhi);
    }
    #pragma unroll
    for (int z = 0; z < 16; ++z) {
      float s = sy[z];
      if (z > 0)  s += sy[z-1];
      if (z < 15) s += sy[z+1];
      szy[z] = s;
    }
  }
  #pragma unroll
  for (int c = 0; c < 4; ++c)
    bufT[COL_IDX(c, x)] = make_float4(szy[4*c], szy[4*c+1], szy[4*c+2], szy[4*c+3]);
  __syncthreads();                                             // S1

  unsigned pm_bdr = 0u;
  #pragma unroll
  for (int c = 0; c < 4; ++c) {
    float4 a4 = bufT[COL_IDX(c, x - 1)];
    float4 b4 = bufT[COL_IDX(c, x + 1)];
    float sm0 = a4.x + b4.x, sm1 = a4.y + b4.y, sm2 = a4.z + b4.z, sm3 = a4.w + b4.w;
    float bb0 = fmaf(27.f, p[4*c+0], -(szy[4*c+0] + sm0));
    float bb1 = fmaf(27.f, p[4*c+1], -(szy[4*c+1] + sm1));
    float bb2 = fmaf(27.f, p[4*c+2], -(szy[4*c+2] + sm2));
    float bb3 = fmaf(27.f, p[4*c+3], -(szy[4*c+3] + sm3));
    if (bb0 > 0.1f) pm_bdr |= (1u << (4*c+0));
    if (bb1 > 0.1f) pm_bdr |= (1u << (4*c+1));
    if (bb2 > 0.1f) pm_bdr |= (1u << (4*c+2));
    if (bb3 > 0.1f) pm_bdr |= (1u << (4*c+3));
  }
  __syncthreads();                                             // S2
  if (tid < 128) {   // bufT pads become -INF (dilate identity)
    const int c  = tid >> 5;
    const int xi = ((tid >> 4) & 1) ? 17 : 0;
    const int yy = tid & 15;
    bufT[(c * 18 + xi) * 16 + yy] = make_float4(-INF, -INF, -INF, -INF);
  }

  // ---------------- pred soft skeleton (4x erode+dilate) ----------------
  float cur[16], skl[16];
  #pragma unroll
  for (int z = 0; z < 16; ++z) { cur[z] = p[z]; skl[z] = 0.f; }

  for (int k = 0; k < 4; ++k) {
    float xm[16], xp[16], en[16];
    #pragma unroll
    for (int c = 0; c < 4; ++c) {
      float4 a4 = bufE[COL_IDX(c, x - 1)];
      float4 b4 = bufE[COL_IDX(c, x + 1)];
      xm[4*c] = a4.x; xm[4*c+1] = a4.y; xm[4*c+2] = a4.z; xm[4*c+3] = a4.w;
      xp[4*c] = b4.x; xp[4*c+1] = b4.y; xp[4*c+2] = b4.z; xp[4*c+3] = b4.w;
    }
    // erode: min over 7-point cross, +INF padding
    #pragma unroll
    for (int z = 0; z < 16; ++z) {
      float v = cur[z];
      float m = fminf(v, fminf(nbr_lo_f(v, INF, ylo), nbr_hi_f(v, INF, yhi)));
      if (z > 0)  m = fminf(m, cur[z-1]);
      if (z < 15) m = fminf(m, cur[z+1]);
      en[z] = fminf(m, fminf(xm[z], xp[z]));
    }
    __syncthreads();                                           // S3
    #pragma unroll
    for (int c = 0; c < 4; ++c)
      bufE[COL_IDX(c, x)] = make_float4(en[4*c], en[4*c+1], en[4*c+2], en[4*c+3]);
    // dilate(en): separable 3^3 max, -INF padding; y and z in-register
    float ty[16], tz[16];
    #pragma unroll
    for (int z = 0; z < 16; ++z) {
      float v = en[z];
      ty[z] = fmaxf(v, fmaxf(nbr_lo_f(v, -INF, ylo), nbr_hi_f(v, -INF, yhi)));
    }
    #pragma unroll
    for (int z = 0; z < 16; ++z) {
      float m = ty[z];
      if (z > 0)  m = fmaxf(m, ty[z-1]);
      if (z < 15) m = fmaxf(m, ty[z+1]);
      tz[z] = m;
    }
    __syncthreads();                                           // S4
    #pragma unroll
    for (int c = 0; c < 4; ++c)
      bufT[COL_IDX(c, x)] = make_float4(tz[4*c], tz[4*c+1], tz[4*c+2], tz[4*c+3]);
    __syncthreads();                                           // S5
    #pragma unroll
    for (int c = 0; c < 4; ++c) {
      float4 a4 = bufT[COL_IDX(c, x - 1)];
      float4 b4 = bufT[COL_IDX(c, x + 1)];
      float dm[4] = {fmaxf(a4.x, b4.x), fmaxf(a4.y, b4.y),
                     fmaxf(a4.z, b4.z), fmaxf(a4.w, b4.w)};
      #pragma unroll
      for (int j = 0; j < 4; ++j) {
        const int z = 4*c + j;
        float D = fmaxf(tz[z], dm[j]);
        float delta = fmaxf(cur[z] - D, 0.f);
        skl[z] += fmaxf(fmaf(-skl[z], delta, delta), 0.f);
        cur[z] = en[z];
      }
    }
  }

  // ---------------- gt phase: exact bit-domain morphology ----------------
  float spg = 0.f;
  unsigned gm = 0u;
  {
    float g[16];
    #pragma unroll
    for (int z = 0; z < 16; ++z) g[z] = gtp[base + (size_t)z * 36864];
    #pragma unroll
    for (int z = 0; z < 16; ++z) {
      spg = fmaf(p[z], g[z], spg);
      if (g[z] > 0.5f) gm |= (1u << z);
    }
  }

  // gt boundary: bdr = g & ~AND27(g) with zero padding
  unsigned ly  = gm & nbr_lo_u(gm, 0u, ylo) & nbr_hi_u(gm, 0u, yhi);
  unsigned lzy = ly & (ly >> 1) & ((ly << 1) & 0xFFFFu);
  m_ex[(x + 1) * 16 + y] = lzy;
  if (tid < 32) m_ex[((tid >> 4) ? 17 : 0) * 16 + (tid & 15)] = 0u;
  __syncthreads();                                             // G1
  unsigned gm_bdr = gm & ~(m_ex[x * 16 + y] & lzy & m_ex[(x + 2) * 16 + y]);

  // gt soft skeleton in bits (erode=AND over cross w/ 1-pad, dilate=OR w/ 0-pad)
  unsigned curm = gm, sklm = 0u;
  for (int k = 0; k < 4; ++k) {
    __syncthreads();                                           // G2
    m_ex[(x + 1) * 16 + y] = curm;
    if (tid < 32) m_ex[((tid >> 4) ? 17 : 0) * 16 + (tid & 15)] = 0xFFFFu;
    __syncthreads();                                           // G3
    unsigned em = curm
        & nbr_lo_u(curm, 0xFFFFu, ylo) & nbr_hi_u(curm, 0xFFFFu, yhi)
        & ((curm >> 1) | 0x8000u) & ((curm << 1) | 1u)
        & m_ex[x * 16 + y] & m_ex[(x + 2) * 16 + y];
    em &= 0xFFFFu;
    unsigned dy  = em | nbr_lo_u(em, 0u, ylo) | nbr_hi_u(em, 0u, yhi);
    unsigned dzy = (dy | (dy >> 1) | (dy << 1)) & 0xFFFFu;
    __syncthreads();                                           // G4
    m_ex[(x + 1) * 16 + y] = dzy;
    if (tid < 32) m_ex[((tid >> 4) ? 17 : 0) * 16 + (tid & 15)] = 0u;
    __syncthreads();                                           // G5
    unsigned D = m_ex[x * 16 + y] | dzy | m_ex[(x + 2) * 16 + y];
    sklm |= curm & ~D;
    curm = em;
  }

  // ---------------- per-block reductions ----------------
  float vals[9];
  {
    float tcl = 0.f, scl = 0.f;
    #pragma unroll
    for (int z = 0; z < 16; ++z) {
      scl += skl[z];
      tcl += ((sklm >> z) & 1u) ? skl[z] : 0.f;
    }
    vals[0] = tcl;                                   // sum g_cl * p_cl
    vals[1] = scl;                                   // sum p_cl
    vals[2] = (float)__popc(sklm);                   // sum g_cl
    vals[3] = (float)__popc(pm_bdr & gm_bdr);        // bdr tp
    vals[4] = (float)__popc(pm_bdr);                 // sum p_bdr
    vals[5] = (float)__popc(gm_bdr);                 // sum g_bdr
    vals[6] = spg;                                   // dice: sum p*g
    vals[7] = sp2;                                   // dice: sum p*p
    vals[8] = (float)__popc(gm);                     // dice: sum g*g
  }
  #pragma unroll
  for (int j = 0; j < 9; ++j) {
    float v = vals[j];
    #pragma unroll
    for (int off = 32; off; off >>= 1) v += __shfl_xor(v, off);
    vals[j] = v;
  }
  if ((tid & 63) == 0) {
    #pragma unroll
    for (int j = 0; j < 9; ++j) red[(tid >> 6) * 9 + j] = vals[j];
  }
  __syncthreads();                                             // R1
  if (tid == 0) {
    float t[9];
    #pragma unroll
    for (int j = 0; j < 9; ++j) t[j] = red[j] + red[9 + j] + red[18 + j] + red[27 + j];
    const float s = 1e-8f;
    // boundary tversky
    float tp = t[3], fp = t[4] - t[3], fn = t[5] - t[3];
    float den = fp + fn + s;
    float alpha = 0.5f + 0.5f * ((fp + s) / den);
    float beta  = 0.5f + 0.5f * ((fn + s) / den);
    float lb = 1.f - (tp + s) / (tp + alpha * fp + beta * fn + s);
    // centerline tversky
    float tpc = t[0], fpc = t[1] - t[0], fnc = t[2] - t[0];
    float denc = fpc + fnc + s;
    float alphac = 0.5f + 0.5f * ((fpc + s) / denc);
    float betac  = 0.5f + 0.5f * ((fnc + s) / denc);
    float lc = 1.f - (tpc + s) / (tpc + alphac * fpc + betac * fnc + s);
    float* o = ws + (size_t)b * 8;
    o[0] = lb; o[1] = lc; o[2] = t[6]; o[3] = t[7]; o[4] = t[8];
  }
}

__global__ __launch_bounds__(256)
void finalize_kernel(const float* __restrict__ ws, const float* __restrict__ w1p,
                     const float* __restrict__ w2p, float* __restrict__ out)
{
  __shared__ double red2[20];
  double a[5] = {0.0, 0.0, 0.0, 0.0, 0.0};
  for (int i = threadIdx.x; i < NBLK; i += 256) {
    const float* o = ws + (size_t)i * 8;
    a[0] += (double)o[0];
    a[1] += (double)o[1];
    a[2] += (double)o[2];
    a[3] += (double)o[3];
    a[4] += (double)o[4];
  }
  #pragma unroll
  for (int j = 0; j < 5; ++j) {
    double v = a[j];
    #pragma unroll
    for (int off = 32; off; off >>= 1) v += __shfl_xor(v, off);
    if ((threadIdx.x & 63) == 0) red2[(threadIdx.x >> 6) * 5 + j] = v;
  }
  __syncthreads();
  if (threadIdx.x == 0) {
    double t[5];
    #pragma unroll
    for (int j = 0; j < 5; ++j) t[j] = red2[j] + red2[5 + j] + red2[10 + j] + red2[15 + j];
    double denom = t[3] + t[4];
    if (denom < 1e-6) denom = 1e-6;
    double dice = 2.0 * t[2] / denom;
    double dl = 1.0 - dice;
    double w1 = (double)w1p[0], w2 = (double)w2p[0];
    double edge = (t[0] / (w1 * w1) + t[1] / (w2 * w2)) / (2.0 * (double)NBLK)
                + log(1.0 + fabs(w1) * fabs(w2));
    out[0] = (float)((dice < 0.8) ? dl : (dl + edge));
  }
}

extern "C" void kernel_launch(void* const* d_in, const int* in_sizes, int n_in,
                              void* d_out, int out_size, void* d_ws, size_t ws_size,
                              hipStream_t stream)
{
  const float* pred = (const float*)d_in[0];
  const float* gtp  = (const float*)d_in[1];
  const float* w1   = (const float*)d_in[2];
  const float* w2   = (const float*)d_in[3];
  float* ws = (float*)d_ws;   // NBLK * 8 floats = 110,592 B

  fused_blocks<<<NBLK, 256, 0, stream>>>(pred, gtp, ws);
  finalize_kernel<<<1, 256, 0, stream>>>(ws, w1, w2, (float*)d_out);
}